// Round 8
// baseline (556.826 us; speedup 1.0000x reference)
//
#include <hip/hip_runtime.h>

#define NEG_SLOPE 0.2f

typedef float f32x4 __attribute__((ext_vector_type(4)));
typedef short bf16x8 __attribute__((ext_vector_type(8)));

__device__ __forceinline__ float lrelu(float x) { return x > 0.0f ? x : NEG_SLOPE * x; }

// pack two floats as bf16 (RNE) into one uint: low16 = a, high16 = b
__device__ __forceinline__ unsigned pack_bf16(float a, float b) {
  unsigned ua = __float_as_uint(a), ub = __float_as_uint(b);
  ua += 0x7fffu + ((ua >> 16) & 1u);
  ub += 0x7fffu + ((ub >> 16) & 1u);
  return (ua >> 16) | (ub & 0xffff0000u);
}
__device__ __forceinline__ unsigned short bf16of(float a) {
  unsigned ua = __float_as_uint(a);
  ua += 0x7fffu + ((ua >> 16) & 1u);
  return (unsigned short)(ua >> 16);
}
__device__ __forceinline__ float bf16lo(unsigned z) { return __uint_as_float(z << 16); }
__device__ __forceinline__ float bf16hi(unsigned z) { return __uint_as_float(z & 0xffff0000u); }

// ---------------------------------------------------------------------------
// K0: fold all small weights. Wzb = bf16(W @ proj_W) in MFMA-B-fragment
// layout: element (k,n) at ((k>>3)*128 + n)*8 + (k&7).
// ---------------------------------------------------------------------------
__global__ void k0_setup(const float* __restrict__ W, const float* __restrict__ proj_W,
                         const float* __restrict__ att_src, const float* __restrict__ att_dst,
                         const float* __restrict__ lin_edge_W, const float* __restrict__ att_edge,
                         const float* __restrict__ bias, const float* __restrict__ proj_b,
                         unsigned short* __restrict__ Wzb, float* __restrict__ Ws,
                         float* __restrict__ Wd, float* __restrict__ M, float* __restrict__ cproj) {
  int t = blockIdx.x * blockDim.x + threadIdx.x;
  if (t < 16384) {
    int d = t >> 7, o = t & 127;
    int h = o >> 5, jj = o & 31;
    float s = 0.f;
    #pragma unroll
    for (int c = 0; c < 32; ++c)
      s += W[d * 128 + h * 32 + c] * proj_W[(h * 32 + c) * 32 + jj];
    Wzb[((d >> 3) * 128 + o) * 8 + (d & 7)] = bf16of(s);
  } else if (t < 16384 + 512) {
    int idx = t - 16384; int d = idx >> 2, h = idx & 3;
    float s = 0.f;
    #pragma unroll
    for (int c = 0; c < 32; ++c) s += W[d * 128 + h * 32 + c] * att_src[h * 32 + c];
    Ws[d * 4 + h] = s;
  } else if (t < 16384 + 1024) {
    int idx = t - 16384 - 512; int d = idx >> 2, h = idx & 3;
    float s = 0.f;
    #pragma unroll
    for (int c = 0; c < 32; ++c) s += W[d * 128 + h * 32 + c] * att_dst[h * 32 + c];
    Wd[d * 4 + h] = s;
  } else if (t < 16384 + 1024 + 128) {
    int idx = t - 16384 - 1024; int d = idx >> 2, h = idx & 3;
    float s = 0.f;
    #pragma unroll
    for (int c = 0; c < 32; ++c) s += lin_edge_W[d * 128 + h * 32 + c] * att_edge[h * 32 + c];
    M[d * 4 + h] = s;
  } else if (t < 16384 + 1024 + 128 + 32) {
    int jj = t - 16384 - 1024 - 128;
    float s = proj_b[jj];
    #pragma unroll
    for (int k = 0; k < 128; ++k) s += bias[k] * proj_W[k * 32 + jj];
    cproj[jj] = s;
  }
}

// ---------------------------------------------------------------------------
// K3a: a_src | a_dst only (f32, bit-exact with previous rounds).
// ---------------------------------------------------------------------------
__global__ __launch_bounds__(256) void k3a_att(
    const float* __restrict__ x, const float* __restrict__ Ws, const float* __restrict__ Wd,
    int n, float* __restrict__ a_src, float* __restrict__ a_dst) {
  int tid = threadIdx.x;
  int lane = tid & 63, wid = tid >> 6;
  float ws0[4], ws1[4], wd0[4], wd1[4];
  #pragma unroll
  for (int h = 0; h < 4; ++h) {
    ws0[h] = Ws[lane * 4 + h];  ws1[h] = Ws[(64 + lane) * 4 + h];
    wd0[h] = Wd[lane * 4 + h];  wd1[h] = Wd[(64 + lane) * 4 + h];
  }
  int gw = blockIdx.x * 4 + wid;
  int nw = gridDim.x * 4;
  for (int base = gw * 4; base < n; base += nw * 4) {
    float xa[4], xb[4];
    #pragma unroll
    for (int u = 0; u < 4; ++u) {
      int node = base + u;
      xa[u] = (node < n) ? x[(size_t)node * 128 + lane] : 0.0f;
      xb[u] = (node < n) ? x[(size_t)node * 128 + 64 + lane] : 0.0f;
    }
    #pragma unroll
    for (int u = 0; u < 4; ++u) {
      int node = base + u;
      if (node >= n) break;
      float ps[4], pd[4];
      #pragma unroll
      for (int h = 0; h < 4; ++h) {
        ps[h] = xa[u] * ws0[h] + xb[u] * ws1[h];
        pd[h] = xa[u] * wd0[h] + xb[u] * wd1[h];
      }
      #pragma unroll
      for (int m = 1; m < 64; m <<= 1) {
        #pragma unroll
        for (int h = 0; h < 4; ++h) {
          ps[h] += __shfl_xor(ps[h], m);
          pd[h] += __shfl_xor(pd[h], m);
        }
      }
      if (lane == 0) {
        *(float4*)&a_src[node * 4] = make_float4(ps[0], ps[1], ps[2], ps[3]);
        *(float4*)&a_dst[node * 4] = make_float4(pd[0], pd[1], pd[2], pd[3]);
      }
    }
  }
}

// ---------------------------------------------------------------------------
// K3b: Zp = bf16pack(x @ Wz) via MFMA 16x16x32 bf16 (round-7 version).
// ---------------------------------------------------------------------------
__global__ __launch_bounds__(256) void k3b_gemm(
    const float* __restrict__ x, const unsigned short* __restrict__ Wzb,
    int n, unsigned* __restrict__ Zp) {
  __shared__ __align__(16) unsigned short WzL[16384];
  int tid = threadIdx.x;
  #pragma unroll
  for (int i = 0; i < 8; ++i)
    *(uint4*)&WzL[(i * 256 + tid) * 8] = *(const uint4*)&Wzb[(i * 256 + tid) * 8];
  __syncthreads();
  int lane = tid & 63, wid = tid >> 6;
  int rgrp = lane >> 4, rl = lane & 15;
  int r0 = blockIdx.x * 64 + wid * 16;
  if (r0 >= n) return;
  int row = r0 + rl; if (row >= n) row = n - 1;
  const float* xr = x + (size_t)row * 128 + rgrp * 8;
  bf16x8 a[4];
  #pragma unroll
  for (int q = 0; q < 4; ++q) {
    float4 v0 = *(const float4*)(xr + q * 32);
    float4 v1 = *(const float4*)(xr + q * 32 + 4);
    union { unsigned u[4]; bf16x8 v; } fa;
    fa.u[0] = pack_bf16(v0.x, v0.y); fa.u[1] = pack_bf16(v0.z, v0.w);
    fa.u[2] = pack_bf16(v1.x, v1.y); fa.u[3] = pack_bf16(v1.z, v1.w);
    a[q] = fa.v;
  }
  f32x4 acc[8];
  #pragma unroll
  for (int t = 0; t < 8; ++t) acc[t] = (f32x4){0.f, 0.f, 0.f, 0.f};
  #pragma unroll
  for (int q = 0; q < 4; ++q) {
    #pragma unroll
    for (int t = 0; t < 8; ++t) {
      bf16x8 b = *(const bf16x8*)&WzL[((q * 4 + rgrp) * 128 + t * 16 + rl) * 8];
      acc[t] = __builtin_amdgcn_mfma_f32_16x16x32_bf16(a[q], b, acc[t], 0, 0, 0);
    }
  }
  #pragma unroll
  for (int t = 0; t < 4; ++t) {
    #pragma unroll
    for (int r = 0; r < 4; ++r) {
      int rr = r0 + rgrp * 4 + r;
      if (rr < n)
        Zp[(size_t)rr * 64 + t * 16 + rl] = pack_bf16(acc[t][r], acc[t + 4][r]);
    }
  }
}

// ---------------------------------------------------------------------------
// K1a: PURE ea->ae stream. Coalesced reads + in-register wave transpose +
// bpermute un-permute -> lane l owns edge T0+l -> fully coalesced 8B writes.
// No gathers, no atomics, no exp: pure streaming kernel; should run at BW.
// ---------------------------------------------------------------------------
__global__ __launch_bounds__(256) void k1a_ae(
    const float4* __restrict__ ea4, const float* __restrict__ Mg, int E,
    uint2* __restrict__ ae8) {
  int lane = threadIdx.x & 63, wid = threadIdx.x >> 6;
  int j = lane & 7;
  const float4* Mf4 = (const float4*)Mg;
  float4 m0 = Mf4[4 * j + 0], m1 = Mf4[4 * j + 1];
  float4 m2 = Mf4[4 * j + 2], m3 = Mf4[4 * j + 3];
  int perm = 8 * (lane & 7) + (lane >> 3);  // involution: perm(perm(l)) == l
  int gw = blockIdx.x * 4 + wid, nw = gridDim.x * 4;
  int ntiles = (E + 63) >> 6;
  for (int tile = gw; tile < ntiles; tile += nw) {
    int T0 = tile << 6;
    size_t fbase = (size_t)T0 * 8;
    float cx = 0.f, cy = 0.f, cz = 0.f, cw = 0.f;
    #pragma unroll
    for (int k = 0; k < 8; ++k) {
      size_t idx = fbase + (size_t)k * 64 + lane;
      float4 v = (idx < (size_t)E * 8) ? ea4[idx] : make_float4(0.f, 0.f, 0.f, 0.f);
      float px = v.x * m0.x + v.y * m1.x + v.z * m2.x + v.w * m3.x;
      float py = v.x * m0.y + v.y * m1.y + v.z * m2.y + v.w * m3.y;
      float pz = v.x * m0.z + v.y * m1.z + v.z * m2.z + v.w * m3.z;
      float pw = v.x * m0.w + v.y * m1.w + v.z * m2.w + v.w * m3.w;
      #pragma unroll
      for (int m = 1; m < 8; m <<= 1) {
        px += __shfl_xor(px, m); py += __shfl_xor(py, m);
        pz += __shfl_xor(pz, m); pw += __shfl_xor(pw, m);
      }
      if (j == k) { cx = px; cy = py; cz = pz; cw = pw; }
    }
    // lane l holds edge T0+perm(l); un-permute so lane l holds edge T0+l
    unsigned p01 = pack_bf16(cx, cy), p23 = pack_bf16(cz, cw);
    p01 = (unsigned)__shfl((int)p01, perm, 64);
    p23 = (unsigned)__shfl((int)p23, perm, 64);
    int e = T0 + lane;
    if (e < E) ae8[e] = make_uint2(p01, p23);
  }
}

// ---------------------------------------------------------------------------
// K1b: per-edge epilogue. ALL array accesses coalesced (ei, ae8, we, rank);
// only the a_src/a_dst gathers + deg atomic are random (L2/L3-resident).
// Tiny VGPR, no LDS -> 32 waves/CU pure latency hiding.
// ---------------------------------------------------------------------------
__global__ __launch_bounds__(256) void k1b_edge(
    const int* __restrict__ ei, int E, const uint2* __restrict__ ae8,
    const float* __restrict__ a_src, const float* __restrict__ a_dst,
    uint4* __restrict__ we, int* __restrict__ deg, int* __restrict__ rank) {
  int e = blockIdx.x * 256 + threadIdx.x;
  if (e >= E) return;
  int s = ei[e], d = ei[E + e];
  uint2 ae = ae8[e];
  float4 as = *(const float4*)&a_src[(size_t)s * 4];
  float4 ad = *(const float4*)&a_dst[(size_t)d * 4];
  int rk = atomicAdd(&deg[d], 1);
  float ae0 = bf16lo(ae.x), ae1 = bf16hi(ae.x);
  float ae2 = bf16lo(ae.y), ae3 = bf16hi(ae.y);
  float w0 = __expf(lrelu(ae0 + as.x + ad.x));
  float w1 = __expf(lrelu(ae1 + as.y + ad.y));
  float w2 = __expf(lrelu(ae2 + as.z + ad.z));
  float w3 = __expf(lrelu(ae3 + as.w + ad.w));
  we[e] = make_uint4(pack_bf16(w0, w1), pack_bf16(w2, w3), ae.x, ae.y);
  rank[e] = rk;
}

// ---------------------------------------------------------------------------
// K2: single-block exclusive scan, all chunk loads hoisted (round-7 version).
// ---------------------------------------------------------------------------
__global__ __launch_bounds__(1024) void k2_scan(const int* __restrict__ deg, int n,
                                                int* __restrict__ offsets) {
  __shared__ int shw[16];
  __shared__ int shtot;
  int tid = threadIdx.x;
  int lane = tid & 63, wid = tid >> 6;
  int nch = (n + 4095) >> 12;
  int4 v[16];
  #pragma unroll
  for (int c = 0; c < 16; ++c) {
    if (c < nch) {
      int i = c * 4096 + tid * 4;
      int4 t = make_int4(0, 0, 0, 0);
      if (i + 3 < n) t = *(const int4*)&deg[i];
      else {
        if (i < n) t.x = deg[i];
        if (i + 1 < n) t.y = deg[i + 1];
        if (i + 2 < n) t.z = deg[i + 2];
        if (i + 3 < n) t.w = deg[i + 3];
      }
      v[c] = t;
    }
  }
  int running = 0;
  #pragma unroll
  for (int c = 0; c < 16; ++c) {
    if (c < nch) {
      int i = c * 4096 + tid * 4;
      int4 t = v[c];
      int tsum = t.x + t.y + t.z + t.w;
      int inc = tsum;
      #pragma unroll
      for (int s = 1; s < 64; s <<= 1) {
        int q = __shfl_up(inc, s);
        if (lane >= s) inc += q;
      }
      if (lane == 63) shw[wid] = inc;
      __syncthreads();
      if (wid == 0) {
        int w = (lane < 16) ? shw[lane] : 0;
        int winc = w;
        #pragma unroll
        for (int s = 1; s < 16; s <<= 1) {
          int q = __shfl_up(winc, s);
          if (lane >= s) winc += q;
        }
        if (lane < 16) shw[lane] = winc - w;
        if (lane == 15) shtot = winc;
      }
      __syncthreads();
      int excl = running + shw[wid] + inc - tsum;
      if (i < n)     offsets[i + 1] = excl + t.x;
      if (i + 1 < n) offsets[i + 2] = excl + t.x + t.y;
      if (i + 2 < n) offsets[i + 3] = excl + t.x + t.y + t.z;
      if (i + 3 < n) offsets[i + 4] = excl + tsum;
      running += shtot;
      __syncthreads();
    }
  }
  if (tid == 0) offsets[0] = 0;
}

// ---------------------------------------------------------------------------
// K4: scatter one 32B CSR entry per edge (plain stores; L2/L3 coalesce).
// ---------------------------------------------------------------------------
__global__ void k4_scatter(const int* __restrict__ ei, int E,
                           const int* __restrict__ rank, const int* __restrict__ offsets,
                           const uint4* __restrict__ we, uint4* __restrict__ csr) {
  int e = blockIdx.x * blockDim.x + threadIdx.x;
  if (e >= E) return;
  int s = ei[e], d = ei[E + e];
  int slot = offsets[d] + rank[e];
  uint4 w = we[e];
  uint4* ent = &csr[(size_t)slot * 2];
  *(int*)ent = s;
  ent[1] = w;
}

// ---------------------------------------------------------------------------
// K5: wave-per-node (round-0/5 form).
// ---------------------------------------------------------------------------
__global__ __launch_bounds__(256) void k5_agg(
    const int* __restrict__ offsets, const uint4* __restrict__ csr,
    const unsigned* __restrict__ Zp,
    const float* __restrict__ a_src, const float* __restrict__ a_dst,
    const float* __restrict__ cproj, int n, float* __restrict__ out) {
  __shared__ float4 s_w[4][64];
  __shared__ int    s_s[4][64];
  int tid = threadIdx.x;
  int lane = tid & 63, wid = tid >> 6;
  int gw = blockIdx.x * 4 + wid, nw = gridDim.x * 4;
  int h0 = lane >> 5, j = lane & 31;
  float cp = cproj[j];
  const float* wbase = (const float*)&s_w[wid][0];
  for (int node = gw; node < n; node += nw) {
    int off0 = offsets[node], off1 = offsets[node + 1];
    int dg = off1 - off0;
    float dsx = 0.f, dsy = 0.f, dsz = 0.f, dsw = 0.f;
    float aex = 0.f, aey = 0.f, aez = 0.f, aew = 0.f;
    float agg0 = 0.f, agg1 = 0.f;
    for (int base = off0; base < off1; base += 64) {
      int rem = off1 - base; if (rem > 64) rem = 64;
      if (lane < rem) {
        const uint4* ent = &csr[(size_t)(base + lane) * 2];
        int s = *(const int*)ent;
        uint4 w = ent[1];
        float w0 = bf16lo(w.x), w1 = bf16hi(w.x);
        float w2 = bf16lo(w.y), w3 = bf16hi(w.y);
        dsx += w0; dsy += w1; dsz += w2; dsw += w3;
        aex += bf16lo(w.z); aey += bf16hi(w.z);
        aez += bf16lo(w.w); aew += bf16hi(w.w);
        s_w[wid][lane] = make_float4(w0, w2, w1, w3);
        s_s[wid][lane] = s;
      }
      int jj = 0;
      for (; jj + 4 <= rem; jj += 4) {
        int s0 = s_s[wid][jj], s1 = s_s[wid][jj + 1];
        int s2 = s_s[wid][jj + 2], s3 = s_s[wid][jj + 3];
        unsigned z0 = Zp[(size_t)s0 * 64 + lane];
        unsigned z1 = Zp[(size_t)s1 * 64 + lane];
        unsigned z2 = Zp[(size_t)s2 * 64 + lane];
        unsigned z3 = Zp[(size_t)s3 * 64 + lane];
        float2 w0 = *(const float2*)(wbase + (jj    ) * 4 + 2 * h0);
        float2 w1 = *(const float2*)(wbase + (jj + 1) * 4 + 2 * h0);
        float2 w2 = *(const float2*)(wbase + (jj + 2) * 4 + 2 * h0);
        float2 w3 = *(const float2*)(wbase + (jj + 3) * 4 + 2 * h0);
        agg0 += w0.x * bf16lo(z0) + w1.x * bf16lo(z1) + w2.x * bf16lo(z2) + w3.x * bf16lo(z3);
        agg1 += w0.y * bf16hi(z0) + w1.y * bf16hi(z1) + w2.y * bf16hi(z2) + w3.y * bf16hi(z3);
      }
      for (; jj < rem; ++jj) {
        int s0 = s_s[wid][jj];
        unsigned z0 = Zp[(size_t)s0 * 64 + lane];
        float2 w0 = *(const float2*)(wbase + jj * 4 + 2 * h0);
        agg0 += w0.x * bf16lo(z0);
        agg1 += w0.y * bf16hi(z0);
      }
    }
    #pragma unroll
    for (int m = 1; m < 64; m <<= 1) {
      dsx += __shfl_xor(dsx, m); dsy += __shfl_xor(dsy, m);
      dsz += __shfl_xor(dsz, m); dsw += __shfl_xor(dsw, m);
      aex += __shfl_xor(aex, m); aey += __shfl_xor(aey, m);
      aez += __shfl_xor(aez, m); aew += __shfl_xor(aew, m);
    }
    float invd = 1.0f / (float)(dg > 0 ? dg : 1);
    float4 asn = *(const float4*)&a_src[node * 4];
    float4 ad  = *(const float4*)&a_dst[node * 4];
    float w0 = __expf(lrelu(asn.x + ad.x + aex * invd));
    float w1 = __expf(lrelu(asn.y + ad.y + aey * invd));
    float w2 = __expf(lrelu(asn.z + ad.z + aez * invd));
    float w3 = __expf(lrelu(asn.w + ad.w + aew * invd));
    dsx += w0; dsy += w1; dsz += w2; dsw += w3;
    unsigned zpn = Zp[(size_t)node * 64 + lane];
    float sw0 = h0 ? w1 : w0, sw1 = h0 ? w3 : w2;
    agg0 += sw0 * bf16lo(zpn);
    agg1 += sw1 * bf16hi(zpn);
    float d0 = h0 ? dsy : dsx, d1 = h0 ? dsw : dsz;
    float tt = agg0 / (d0 + 1e-16f) + agg1 / (d1 + 1e-16f);
    tt += __shfl_xor(tt, 32);
    if (lane < 32) out[node * 32 + j] = tt + cp;
  }
}

// ---------------------------------------------------------------------------
extern "C" void kernel_launch(void* const* d_in, const int* in_sizes, int n_in,
                              void* d_out, int out_size, void* d_ws, size_t ws_size,
                              hipStream_t stream) {
  const float* x          = (const float*)d_in[0];
  const int*   ei         = (const int*)  d_in[1];
  const float* ea         = (const float*)d_in[2];
  const float* W          = (const float*)d_in[3];
  const float* att_src    = (const float*)d_in[4];
  const float* att_dst    = (const float*)d_in[5];
  const float* lin_edge_W = (const float*)d_in[6];
  const float* att_edge   = (const float*)d_in[7];
  const float* bias       = (const float*)d_in[8];
  const float* proj_W     = (const float*)d_in[9];
  const float* proj_b     = (const float*)d_in[10];
  float* out = (float*)d_out;
  int N = in_sizes[0] / 128;
  int E = in_sizes[1] / 2;

  char* p = (char*)d_ws;
  auto alloc = [&](size_t bytes) {
    char* r = p;
    p += (bytes + 255) & ~(size_t)255;
    return r;
  };
  unsigned* Zp          = (unsigned*)alloc((size_t)N * 64 * 4);
  float* a_src          = (float*)alloc((size_t)N * 4 * 4);
  float* a_dst          = (float*)alloc((size_t)N * 4 * 4);
  int*   deg            = (int*)  alloc((size_t)N * 4);
  int*   offsets        = (int*)  alloc((size_t)(N + 1) * 4);
  int*   rank           = (int*)  alloc((size_t)E * 4);
  uint2* ae8            = (uint2*)alloc((size_t)E * 8);
  uint4* we             = (uint4*)alloc((size_t)E * 16);
  uint4* csr            = (uint4*)alloc((size_t)E * 32);
  unsigned short* Wzb   = (unsigned short*)alloc(16384 * 2);
  float* Ws             = (float*)alloc(128 * 4 * 4);
  float* Wd             = (float*)alloc(128 * 4 * 4);
  float* M              = (float*)alloc(32 * 4 * 4);
  float* cproj          = (float*)alloc(32 * 4);

  hipMemsetAsync(deg, 0, (size_t)N * 4, stream);

  k0_setup<<<69, 256, 0, stream>>>(W, proj_W, att_src, att_dst, lin_edge_W, att_edge,
                                   bias, proj_b, Wzb, Ws, Wd, M, cproj);
  k1a_ae<<<2048, 256, 0, stream>>>((const float4*)ea, M, E, ae8);
  k3a_att<<<512, 256, 0, stream>>>(x, Ws, Wd, N, a_src, a_dst);
  k3b_gemm<<<(N + 63) / 64, 256, 0, stream>>>(x, Wzb, N, Zp);
  k1b_edge<<<(E + 255) / 256, 256, 0, stream>>>(ei, E, ae8, a_src, a_dst, we, deg, rank);
  k2_scan<<<1, 1024, 0, stream>>>(deg, N, offsets);
  k4_scatter<<<(E + 255) / 256, 256, 0, stream>>>(ei, E, rank, offsets, we, csr);
  k5_agg<<<2048, 256, 0, stream>>>(offsets, csr, Zp, a_src, a_dst, cproj, N, out);
}

// Round 9
// 487.118 us; speedup vs baseline: 1.1431x; 1.1431x over previous
//
#include <hip/hip_runtime.h>

#define NEG_SLOPE 0.2f

typedef float f32x4 __attribute__((ext_vector_type(4)));
typedef short bf16x8 __attribute__((ext_vector_type(8)));

__device__ __forceinline__ float lrelu(float x) { return x > 0.0f ? x : NEG_SLOPE * x; }

// pack two floats as bf16 (RNE) into one uint: low16 = a, high16 = b
__device__ __forceinline__ unsigned pack_bf16(float a, float b) {
  unsigned ua = __float_as_uint(a), ub = __float_as_uint(b);
  ua += 0x7fffu + ((ua >> 16) & 1u);
  ub += 0x7fffu + ((ub >> 16) & 1u);
  return (ua >> 16) | (ub & 0xffff0000u);
}
__device__ __forceinline__ unsigned short bf16of(float a) {
  unsigned ua = __float_as_uint(a);
  ua += 0x7fffu + ((ua >> 16) & 1u);
  return (unsigned short)(ua >> 16);
}
__device__ __forceinline__ float bf16lo(unsigned z) { return __uint_as_float(z << 16); }
__device__ __forceinline__ float bf16hi(unsigned z) { return __uint_as_float(z & 0xffff0000u); }

// ---------------------------------------------------------------------------
// K0: fold all small weights. Wzb = bf16(W @ proj_W) in MFMA-B-fragment
// layout: element (k,n) at ((k>>3)*128 + n)*8 + (k&7).
// ---------------------------------------------------------------------------
__global__ void k0_setup(const float* __restrict__ W, const float* __restrict__ proj_W,
                         const float* __restrict__ att_src, const float* __restrict__ att_dst,
                         const float* __restrict__ lin_edge_W, const float* __restrict__ att_edge,
                         const float* __restrict__ bias, const float* __restrict__ proj_b,
                         unsigned short* __restrict__ Wzb, float* __restrict__ Ws,
                         float* __restrict__ Wd, float* __restrict__ M, float* __restrict__ cproj) {
  int t = blockIdx.x * blockDim.x + threadIdx.x;
  if (t < 16384) {
    int d = t >> 7, o = t & 127;
    int h = o >> 5, jj = o & 31;
    float s = 0.f;
    #pragma unroll
    for (int c = 0; c < 32; ++c)
      s += W[d * 128 + h * 32 + c] * proj_W[(h * 32 + c) * 32 + jj];
    Wzb[((d >> 3) * 128 + o) * 8 + (d & 7)] = bf16of(s);
  } else if (t < 16384 + 512) {
    int idx = t - 16384; int d = idx >> 2, h = idx & 3;
    float s = 0.f;
    #pragma unroll
    for (int c = 0; c < 32; ++c) s += W[d * 128 + h * 32 + c] * att_src[h * 32 + c];
    Ws[d * 4 + h] = s;
  } else if (t < 16384 + 1024) {
    int idx = t - 16384 - 512; int d = idx >> 2, h = idx & 3;
    float s = 0.f;
    #pragma unroll
    for (int c = 0; c < 32; ++c) s += W[d * 128 + h * 32 + c] * att_dst[h * 32 + c];
    Wd[d * 4 + h] = s;
  } else if (t < 16384 + 1024 + 128) {
    int idx = t - 16384 - 1024; int d = idx >> 2, h = idx & 3;
    float s = 0.f;
    #pragma unroll
    for (int c = 0; c < 32; ++c) s += lin_edge_W[d * 128 + h * 32 + c] * att_edge[h * 32 + c];
    M[d * 4 + h] = s;
  } else if (t < 16384 + 1024 + 128 + 32) {
    int jj = t - 16384 - 1024 - 128;
    float s = proj_b[jj];
    #pragma unroll
    for (int k = 0; k < 128; ++k) s += bias[k] * proj_W[k * 32 + jj];
    cproj[jj] = s;
  }
}

// ---------------------------------------------------------------------------
// K3: fused. Zp = bf16pack(x @ Wz) via MFMA 16x16x32 bf16, AND a_src/a_dst
// computed from the SAME f32 x registers before bf16 packing (Ws/Wd in LDS,
// in-lane 32-sum + 2-step cross-lane reduce over rgrp). One x pass total.
// ---------------------------------------------------------------------------
__global__ __launch_bounds__(256) void k3_gemm(
    const float* __restrict__ x, const unsigned short* __restrict__ Wzb,
    const float* __restrict__ Ws, const float* __restrict__ Wd,
    int n, unsigned* __restrict__ Zp, float* __restrict__ a_src, float* __restrict__ a_dst) {
  __shared__ __align__(16) unsigned short WzL[16384];
  __shared__ float4 WsL[128];
  __shared__ float4 WdL[128];
  int tid = threadIdx.x;
  #pragma unroll
  for (int i = 0; i < 8; ++i)
    *(uint4*)&WzL[(i * 256 + tid) * 8] = *(const uint4*)&Wzb[(i * 256 + tid) * 8];
  if (tid < 128) {
    WsL[tid] = ((const float4*)Ws)[tid];
    WdL[tid] = ((const float4*)Wd)[tid];
  }
  __syncthreads();
  int lane = tid & 63, wid = tid >> 6;
  int rgrp = lane >> 4, rl = lane & 15;
  int r0 = blockIdx.x * 64 + wid * 16;
  if (r0 >= n) return;
  int row = r0 + rl;
  bool rowok = row < n;
  int rowc = rowok ? row : n - 1;
  const float* xr = x + (size_t)rowc * 128 + rgrp * 8;
  bf16x8 a[4];
  float ps[4] = {0.f, 0.f, 0.f, 0.f}, pd[4] = {0.f, 0.f, 0.f, 0.f};
  #pragma unroll
  for (int q = 0; q < 4; ++q) {
    float4 v0 = *(const float4*)(xr + q * 32);
    float4 v1 = *(const float4*)(xr + q * 32 + 4);
    int d0 = q * 32 + rgrp * 8;
    float vv[8] = {v0.x, v0.y, v0.z, v0.w, v1.x, v1.y, v1.z, v1.w};
    #pragma unroll
    for (int i = 0; i < 8; ++i) {
      float4 ws = WsL[d0 + i], wd = WdL[d0 + i];
      ps[0] += vv[i] * ws.x; ps[1] += vv[i] * ws.y;
      ps[2] += vv[i] * ws.z; ps[3] += vv[i] * ws.w;
      pd[0] += vv[i] * wd.x; pd[1] += vv[i] * wd.y;
      pd[2] += vv[i] * wd.z; pd[3] += vv[i] * wd.w;
    }
    union { unsigned u[4]; bf16x8 v; } fa;
    fa.u[0] = pack_bf16(v0.x, v0.y); fa.u[1] = pack_bf16(v0.z, v0.w);
    fa.u[2] = pack_bf16(v1.x, v1.y); fa.u[3] = pack_bf16(v1.z, v1.w);
    a[q] = fa.v;
  }
  // reduce ps/pd across rgrp (lanes {rl, rl+16, rl+32, rl+48} share a row)
  #pragma unroll
  for (int m = 16; m < 64; m <<= 1) {
    #pragma unroll
    for (int h = 0; h < 4; ++h) {
      ps[h] += __shfl_xor(ps[h], m);
      pd[h] += __shfl_xor(pd[h], m);
    }
  }
  if (rgrp == 0 && rowok) {
    *(float4*)&a_src[(size_t)row * 4] = make_float4(ps[0], ps[1], ps[2], ps[3]);
    *(float4*)&a_dst[(size_t)row * 4] = make_float4(pd[0], pd[1], pd[2], pd[3]);
  }
  f32x4 acc[8];
  #pragma unroll
  for (int t = 0; t < 8; ++t) acc[t] = (f32x4){0.f, 0.f, 0.f, 0.f};
  #pragma unroll
  for (int q = 0; q < 4; ++q) {
    #pragma unroll
    for (int t = 0; t < 8; ++t) {
      bf16x8 b = *(const bf16x8*)&WzL[((q * 4 + rgrp) * 128 + t * 16 + rl) * 8];
      acc[t] = __builtin_amdgcn_mfma_f32_16x16x32_bf16(a[q], b, acc[t], 0, 0, 0);
    }
  }
  #pragma unroll
  for (int t = 0; t < 4; ++t) {
    #pragma unroll
    for (int r = 0; r < 4; ++r) {
      int rr = r0 + rgrp * 4 + r;
      if (rr < n)
        Zp[(size_t)rr * 64 + t * 16 + rl] = pack_bf16(acc[t][r], acc[t + 4][r]);
    }
  }
}

// ---------------------------------------------------------------------------
// K1: fused edge pass (round-7 semantics) with EXPLICIT MLP: all 8 ea loads
// hoisted into v[8] registers, and the epilogue's ei loads + deg atomic +
// a_src/a_dst gathers issued BEFORE the shuffle-transpose compute so their
// latency hides under ~450 cycles of FMA/shfl work.
// ---------------------------------------------------------------------------
__global__ __launch_bounds__(256) void k1_edge(
    const int* __restrict__ ei, int E, const float4* __restrict__ ea4,
    const float* __restrict__ Mg,
    const float* __restrict__ a_src, const float* __restrict__ a_dst,
    uint4* __restrict__ we, int* __restrict__ deg, int* __restrict__ rank) {
  int lane = threadIdx.x & 63, wid = threadIdx.x >> 6;
  int j = lane & 7;
  const float4* Mf4 = (const float4*)Mg;
  float4 m0 = Mf4[4 * j + 0], m1 = Mf4[4 * j + 1];
  float4 m2 = Mf4[4 * j + 2], m3 = Mf4[4 * j + 3];
  int perm = 8 * (lane & 7) + (lane >> 3);
  int gw = blockIdx.x * 4 + wid, nw = gridDim.x * 4;
  int ntiles = (E + 63) >> 6;
  for (int tile = gw; tile < ntiles; tile += nw) {
    int T0 = tile << 6;
    int e = T0 + perm;
    size_t fbase = (size_t)T0 * 8;
    // ---- issue epilogue index loads first ----
    int s = 0, d = 0;
    bool ok = e < E;
    if (ok) { s = ei[e]; d = ei[E + e]; }
    // ---- issue all 8 stream loads (fast path: full tile, no guards) ----
    float4 v[8];
    if (T0 + 64 <= E) {
      #pragma unroll
      for (int k = 0; k < 8; ++k) v[k] = ea4[fbase + (size_t)k * 64 + lane];
    } else {
      #pragma unroll
      for (int k = 0; k < 8; ++k) {
        size_t idx = fbase + (size_t)k * 64 + lane;
        v[k] = (idx < (size_t)E * 8) ? ea4[idx] : make_float4(0.f, 0.f, 0.f, 0.f);
      }
    }
    // ---- issue atomic + gathers (latency hides under the compute below) ----
    int rk = 0;
    float4 as = make_float4(0.f, 0.f, 0.f, 0.f);
    float4 ad = make_float4(0.f, 0.f, 0.f, 0.f);
    if (ok) {
      rk = atomicAdd(&deg[d], 1);
      as = *(const float4*)&a_src[(size_t)s * 4];
      ad = *(const float4*)&a_dst[(size_t)d * 4];
    }
    // ---- transpose compute ----
    float cx = 0.f, cy = 0.f, cz = 0.f, cw = 0.f;
    #pragma unroll
    for (int k = 0; k < 8; ++k) {
      float px = v[k].x * m0.x + v[k].y * m1.x + v[k].z * m2.x + v[k].w * m3.x;
      float py = v[k].x * m0.y + v[k].y * m1.y + v[k].z * m2.y + v[k].w * m3.y;
      float pz = v[k].x * m0.z + v[k].y * m1.z + v[k].z * m2.z + v[k].w * m3.z;
      float pw = v[k].x * m0.w + v[k].y * m1.w + v[k].z * m2.w + v[k].w * m3.w;
      #pragma unroll
      for (int m = 1; m < 8; m <<= 1) {
        px += __shfl_xor(px, m); py += __shfl_xor(py, m);
        pz += __shfl_xor(pz, m); pw += __shfl_xor(pw, m);
      }
      if (j == k) { cx = px; cy = py; cz = pz; cw = pw; }
    }
    // ---- epilogue ----
    if (ok) {
      float w0 = __expf(lrelu(cx + as.x + ad.x));
      float w1 = __expf(lrelu(cy + as.y + ad.y));
      float w2 = __expf(lrelu(cz + as.z + ad.z));
      float w3 = __expf(lrelu(cw + as.w + ad.w));
      we[e] = make_uint4(pack_bf16(w0, w1), pack_bf16(w2, w3),
                         pack_bf16(cx, cy), pack_bf16(cz, cw));
      rank[e] = rk;
    }
  }
}

// ---------------------------------------------------------------------------
// K2: single-block exclusive scan, all chunk loads hoisted (round-7 version).
// ---------------------------------------------------------------------------
__global__ __launch_bounds__(1024) void k2_scan(const int* __restrict__ deg, int n,
                                                int* __restrict__ offsets) {
  __shared__ int shw[16];
  __shared__ int shtot;
  int tid = threadIdx.x;
  int lane = tid & 63, wid = tid >> 6;
  int nch = (n + 4095) >> 12;
  int4 v[16];
  #pragma unroll
  for (int c = 0; c < 16; ++c) {
    if (c < nch) {
      int i = c * 4096 + tid * 4;
      int4 t = make_int4(0, 0, 0, 0);
      if (i + 3 < n) t = *(const int4*)&deg[i];
      else {
        if (i < n) t.x = deg[i];
        if (i + 1 < n) t.y = deg[i + 1];
        if (i + 2 < n) t.z = deg[i + 2];
        if (i + 3 < n) t.w = deg[i + 3];
      }
      v[c] = t;
    }
  }
  int running = 0;
  #pragma unroll
  for (int c = 0; c < 16; ++c) {
    if (c < nch) {
      int i = c * 4096 + tid * 4;
      int4 t = v[c];
      int tsum = t.x + t.y + t.z + t.w;
      int inc = tsum;
      #pragma unroll
      for (int s = 1; s < 64; s <<= 1) {
        int q = __shfl_up(inc, s);
        if (lane >= s) inc += q;
      }
      if (lane == 63) shw[wid] = inc;
      __syncthreads();
      if (wid == 0) {
        int w = (lane < 16) ? shw[lane] : 0;
        int winc = w;
        #pragma unroll
        for (int s = 1; s < 16; s <<= 1) {
          int q = __shfl_up(winc, s);
          if (lane >= s) winc += q;
        }
        if (lane < 16) shw[lane] = winc - w;
        if (lane == 15) shtot = winc;
      }
      __syncthreads();
      int excl = running + shw[wid] + inc - tsum;
      if (i < n)     offsets[i + 1] = excl + t.x;
      if (i + 1 < n) offsets[i + 2] = excl + t.x + t.y;
      if (i + 2 < n) offsets[i + 3] = excl + t.x + t.y + t.z;
      if (i + 3 < n) offsets[i + 4] = excl + tsum;
      running += shtot;
      __syncthreads();
    }
  }
  if (tid == 0) offsets[0] = 0;
}

// ---------------------------------------------------------------------------
// K4: scatter one 32B CSR entry per edge (plain stores; L2/L3 coalesce).
// ---------------------------------------------------------------------------
__global__ void k4_scatter(const int* __restrict__ ei, int E,
                           const int* __restrict__ rank, const int* __restrict__ offsets,
                           const uint4* __restrict__ we, uint4* __restrict__ csr) {
  int e = blockIdx.x * blockDim.x + threadIdx.x;
  if (e >= E) return;
  int s = ei[e], d = ei[E + e];
  int slot = offsets[d] + rank[e];
  uint4 w = we[e];
  uint4* ent = &csr[(size_t)slot * 2];
  *(int*)ent = s;
  ent[1] = w;
}

// ---------------------------------------------------------------------------
// K5: wave-per-node. Phase A: coalesced CSR stream -> dsum/aeSum partials +
// LDS stash. Phase B: Zp row gathers, UNROLL 8 for memory-level parallelism.
// ---------------------------------------------------------------------------
__global__ __launch_bounds__(256) void k5_agg(
    const int* __restrict__ offsets, const uint4* __restrict__ csr,
    const unsigned* __restrict__ Zp,
    const float* __restrict__ a_src, const float* __restrict__ a_dst,
    const float* __restrict__ cproj, int n, float* __restrict__ out) {
  __shared__ float4 s_w[4][64];
  __shared__ int    s_s[4][64];
  int tid = threadIdx.x;
  int lane = tid & 63, wid = tid >> 6;
  int gw = blockIdx.x * 4 + wid, nw = gridDim.x * 4;
  int h0 = lane >> 5, j = lane & 31;
  float cp = cproj[j];
  const float* wbase = (const float*)&s_w[wid][0];
  for (int node = gw; node < n; node += nw) {
    int off0 = offsets[node], off1 = offsets[node + 1];
    int dg = off1 - off0;
    float dsx = 0.f, dsy = 0.f, dsz = 0.f, dsw = 0.f;
    float aex = 0.f, aey = 0.f, aez = 0.f, aew = 0.f;
    float agg0 = 0.f, agg1 = 0.f;
    for (int base = off0; base < off1; base += 64) {
      int rem = off1 - base; if (rem > 64) rem = 64;
      if (lane < rem) {
        const uint4* ent = &csr[(size_t)(base + lane) * 2];
        int s = *(const int*)ent;
        uint4 w = ent[1];
        float w0 = bf16lo(w.x), w1 = bf16hi(w.x);
        float w2 = bf16lo(w.y), w3 = bf16hi(w.y);
        dsx += w0; dsy += w1; dsz += w2; dsw += w3;
        aex += bf16lo(w.z); aey += bf16hi(w.z);
        aez += bf16lo(w.w); aew += bf16hi(w.w);
        s_w[wid][lane] = make_float4(w0, w2, w1, w3);
        s_s[wid][lane] = s;
      }
      int jj = 0;
      for (; jj + 8 <= rem; jj += 8) {
        int ss[8];
        #pragma unroll
        for (int u = 0; u < 8; ++u) ss[u] = s_s[wid][jj + u];
        unsigned z[8];
        #pragma unroll
        for (int u = 0; u < 8; ++u) z[u] = Zp[(size_t)ss[u] * 64 + lane];
        #pragma unroll
        for (int u = 0; u < 8; ++u) {
          float2 w = *(const float2*)(wbase + (jj + u) * 4 + 2 * h0);
          agg0 += w.x * bf16lo(z[u]);
          agg1 += w.y * bf16hi(z[u]);
        }
      }
      for (; jj < rem; ++jj) {
        int s0 = s_s[wid][jj];
        unsigned z0 = Zp[(size_t)s0 * 64 + lane];
        float2 w0 = *(const float2*)(wbase + jj * 4 + 2 * h0);
        agg0 += w0.x * bf16lo(z0);
        agg1 += w0.y * bf16hi(z0);
      }
    }
    #pragma unroll
    for (int m = 1; m < 64; m <<= 1) {
      dsx += __shfl_xor(dsx, m); dsy += __shfl_xor(dsy, m);
      dsz += __shfl_xor(dsz, m); dsw += __shfl_xor(dsw, m);
      aex += __shfl_xor(aex, m); aey += __shfl_xor(aey, m);
      aez += __shfl_xor(aez, m); aew += __shfl_xor(aew, m);
    }
    float invd = 1.0f / (float)(dg > 0 ? dg : 1);
    float4 asn = *(const float4*)&a_src[node * 4];
    float4 ad  = *(const float4*)&a_dst[node * 4];
    float w0 = __expf(lrelu(asn.x + ad.x + aex * invd));
    float w1 = __expf(lrelu(asn.y + ad.y + aey * invd));
    float w2 = __expf(lrelu(asn.z + ad.z + aez * invd));
    float w3 = __expf(lrelu(asn.w + ad.w + aew * invd));
    dsx += w0; dsy += w1; dsz += w2; dsw += w3;
    unsigned zpn = Zp[(size_t)node * 64 + lane];
    float sw0 = h0 ? w1 : w0, sw1 = h0 ? w3 : w2;
    agg0 += sw0 * bf16lo(zpn);
    agg1 += sw1 * bf16hi(zpn);
    float d0 = h0 ? dsy : dsx, d1 = h0 ? dsw : dsz;
    float tt = agg0 / (d0 + 1e-16f) + agg1 / (d1 + 1e-16f);
    tt += __shfl_xor(tt, 32);
    if (lane < 32) out[node * 32 + j] = tt + cp;
  }
}

// ---------------------------------------------------------------------------
extern "C" void kernel_launch(void* const* d_in, const int* in_sizes, int n_in,
                              void* d_out, int out_size, void* d_ws, size_t ws_size,
                              hipStream_t stream) {
  const float* x          = (const float*)d_in[0];
  const int*   ei         = (const int*)  d_in[1];
  const float* ea         = (const float*)d_in[2];
  const float* W          = (const float*)d_in[3];
  const float* att_src    = (const float*)d_in[4];
  const float* att_dst    = (const float*)d_in[5];
  const float* lin_edge_W = (const float*)d_in[6];
  const float* att_edge   = (const float*)d_in[7];
  const float* bias       = (const float*)d_in[8];
  const float* proj_W     = (const float*)d_in[9];
  const float* proj_b     = (const float*)d_in[10];
  float* out = (float*)d_out;
  int N = in_sizes[0] / 128;
  int E = in_sizes[1] / 2;

  char* p = (char*)d_ws;
  auto alloc = [&](size_t bytes) {
    char* r = p;
    p += (bytes + 255) & ~(size_t)255;
    return r;
  };
  unsigned* Zp          = (unsigned*)alloc((size_t)N * 64 * 4);
  float* a_src          = (float*)alloc((size_t)N * 4 * 4);
  float* a_dst          = (float*)alloc((size_t)N * 4 * 4);
  int*   deg            = (int*)  alloc((size_t)N * 4);
  int*   offsets        = (int*)  alloc((size_t)(N + 1) * 4);
  int*   rank           = (int*)  alloc((size_t)E * 4);
  uint4* we             = (uint4*)alloc((size_t)E * 16);
  uint4* csr            = (uint4*)alloc((size_t)E * 32);
  unsigned short* Wzb   = (unsigned short*)alloc(16384 * 2);
  float* Ws             = (float*)alloc(128 * 4 * 4);
  float* Wd             = (float*)alloc(128 * 4 * 4);
  float* M              = (float*)alloc(32 * 4 * 4);
  float* cproj          = (float*)alloc(32 * 4);

  hipMemsetAsync(deg, 0, (size_t)N * 4, stream);

  k0_setup<<<69, 256, 0, stream>>>(W, proj_W, att_src, att_dst, lin_edge_W, att_edge,
                                   bias, proj_b, Wzb, Ws, Wd, M, cproj);
  k3_gemm<<<(N + 63) / 64, 256, 0, stream>>>(x, Wzb, Ws, Wd, N, Zp, a_src, a_dst);
  k1_edge<<<2048, 256, 0, stream>>>(ei, E, (const float4*)ea, M,
                                    a_src, a_dst, we, deg, rank);
  k2_scan<<<1, 1024, 0, stream>>>(deg, N, offsets);
  k4_scatter<<<(E + 255) / 256, 256, 0, stream>>>(ei, E, rank, offsets, we, csr);
  k5_agg<<<2048, 256, 0, stream>>>(offsets, csr, Zp, a_src, a_dst, cproj, N, out);
}